// Round 5
// baseline (149.892 us; speedup 1.0000x reference)
//
#include <hip/hip_runtime.h>

#define POOL 100
#define PLEN 8
#define EMB 768
#define KEYD 768
#define BATCH 256
#define LD (PLEN*EMB)              // 6144
#define EK_FLOATS (BATCH*4*EMB)    // 786432
#define XB_FLOATS (BATCH*197*EMB)  // 38756352
#define LOSS_OFF (2*EK_FLOATS)     // 1572864
#define XB_OFF (LOSS_OFF+1)        // 1572865 (4B-aligned only!)
#define NGT 325                    // 25*26/2 triangular 4x4 gram tiles
#define NCOS (BATCH*25)            // 6400 cos blocks, 4 waves x 25 k's each
#define NCOMP (NGT+NCOS)           // 6725 compute blocks in kA
#define N4 9689087                 // (XB_FLOATS-3)/4 aligned float4 in copy
#define TILE 2048                  // float4 per copy block (256 thr x 8 iters)
#define NTILES 4731                // ceil(N4/TILE)
#define NCOPY_A 2366               // copy tiles in kernel A
#define NCOPY_B 2365               // copy tiles in kernel B
#define GRID_A (4*NCOPY_A)         // 9464: b%4==0 -> copy, else compute
#define GRID_B (BATCH+NCOPY_B)     // 2621

typedef float v4f __attribute__((ext_vector_type(4)));

// Both-sides-16B-aligned streaming copy tile. dst4[j] = {src4[j].w, src4[j+1].xyz};
// src4[j].w comes from the wave neighbor via shfl_up (wave-lane 0: scalar load).
// Nontemporal: xb/out touched exactly once, keep L2 for p/K/G.
__device__ __forceinline__ void copy_tile(const float* __restrict__ xb,
                                          float* __restrict__ out, int tile) {
    const v4f* src4 = (const v4f*)xb;                // 16B aligned
    v4f* dst4 = (v4f*)(out + XB_OFF + 3);            // 16B aligned
    size_t base = (size_t)tile * TILE + threadIdx.x;
    #pragma unroll
    for (int it = 0; it < 8; ++it) {
        size_t j = base + (size_t)it * 256;
        if (j < N4) {
            v4f v = __builtin_nontemporal_load(&src4[j + 1]);
            float pw = __shfl_up(v[3], 1, 64);       // neighbor's src4[j].w
            if ((threadIdx.x & 63) == 0) pw = xb[4 * j + 3];
            v4f o = {pw, v[0], v[1], v[2]};
            __builtin_nontemporal_store(o, &dst4[j]);
        }
    }
}

// 4x4 row-group gram tile: block computes G[4gy+i][4gx+j] for i,j in 0..3.
// 8 row-loads for 16 dots (4x traffic cut vs pairwise), f64 accumulation.
__device__ __forceinline__ void gram_tile(const float* __restrict__ p,
                                          double* __restrict__ G, int t) {
    int gx = (int)((sqrt(8.0 * t + 1.0) - 1.0) * 0.5);
    while ((gx + 1) * (gx + 2) / 2 <= t) ++gx;
    while (gx * (gx + 1) / 2 > t) --gx;
    int gy = t - gx * (gx + 1) / 2;
    const v4f* P4 = (const v4f*)p;
    double acc[16];
    #pragma unroll
    for (int i = 0; i < 16; ++i) acc[i] = 0.0;
    #pragma unroll
    for (int ch = 0; ch < 6; ++ch) {                 // 1536 float4 cols / 256 thr
        int col = ch * 256 + threadIdx.x;
        v4f ay[4], ax[4];
        #pragma unroll
        for (int i = 0; i < 4; ++i) ay[i] = P4[(size_t)(4*gy + i) * 1536 + col];
        #pragma unroll
        for (int j = 0; j < 4; ++j) ax[j] = P4[(size_t)(4*gx + j) * 1536 + col];
        #pragma unroll
        for (int i = 0; i < 4; ++i)
            #pragma unroll
            for (int j = 0; j < 4; ++j)
                acc[i*4+j] += (double)ay[i][0]*ax[j][0] + (double)ay[i][1]*ax[j][1]
                            + (double)ay[i][2]*ax[j][2] + (double)ay[i][3]*ax[j][3];
    }
    #pragma unroll
    for (int i = 0; i < 16; ++i)
        for (int off = 32; off > 0; off >>= 1)
            acc[i] += __shfl_down(acc[i], off, 64);
    __shared__ double sg[4][16];
    int lane = threadIdx.x & 63, w = threadIdx.x >> 6;
    if (lane == 0) {
        #pragma unroll
        for (int i = 0; i < 16; ++i) sg[w][i] = acc[i];
    }
    __syncthreads();
    if (threadIdx.x < 16) {
        double v = sg[0][threadIdx.x] + sg[1][threadIdx.x]
                 + sg[2][threadIdx.x] + sg[3][threadIdx.x];
        int i = threadIdx.x >> 2, j = threadIdx.x & 3;
        int r = 4*gy + i, c = 4*gx + j;
        G[r * POOL + c] = v;     // diagonal tiles write twice w/ equal values: benign
        G[c * POOL + r] = v;
    }
}

// cos[b,k] = <xq[b],K[k]> / max(||K[k]||,1e-12), one wave per (b,k).
__device__ __forceinline__ void cos_unit(const float* __restrict__ xq,
                                         const float* __restrict__ K,
                                         double* __restrict__ cosm, int c) {
    int b = c / 25, kg = c % 25;
    int w = threadIdx.x >> 6, lane = threadIdx.x & 63;
    int k = kg * 4 + w;                              // < 100 always
    const v4f* kr = (const v4f*)(K + (size_t)k * KEYD);
    const v4f* xr = (const v4f*)(xq + (size_t)b * KEYD);
    double dot = 0.0, sq = 0.0;
    #pragma unroll
    for (int it = 0; it < 3; ++it) {                 // 192 float4 per row
        v4f a = kr[it * 64 + lane];
        v4f x = xr[it * 64 + lane];
        dot += (double)a[0]*x[0] + (double)a[1]*x[1] + (double)a[2]*x[2] + (double)a[3]*x[3];
        sq  += (double)a[0]*a[0] + (double)a[1]*a[1] + (double)a[2]*a[2] + (double)a[3]*a[3];
    }
    for (int off = 32; off > 0; off >>= 1) {
        dot += __shfl_down(dot, off, 64);
        sq  += __shfl_down(sq,  off, 64);
    }
    if (lane == 0)
        cosm[(size_t)b * POOL + k] = dot / fmax(sqrt(sq), 1e-12);
}

// Kernel A: copy tiles INTERLEAVED (every 4th block) with gram tiles + cos units,
// so HBM streaming and latency-bound compute share residency the whole time.
__global__ void kA(const float* __restrict__ p, const float* __restrict__ xq,
                   const float* __restrict__ K, const float* __restrict__ xb,
                   float* __restrict__ out, double* __restrict__ G,
                   double* __restrict__ cosm, double* __restrict__ lossAcc,
                   unsigned int* __restrict__ lossCnt) {
    int b = blockIdx.x;
    if ((b & 3) == 0) {                              // copy lane: tiles 0..NCOPY_A-1
        int tile = b >> 2;
        if (tile == 0) {
            if (threadIdx.x == 64) { lossAcc[0] = 0.0; lossCnt[0] = 0u; }
            if (threadIdx.x == 65) {
                out[XB_OFF]     = xb[0];
                out[XB_OFF + 1] = xb[1];
                out[XB_OFF + 2] = xb[2];
                out[XB_OFF + XB_FLOATS - 1] = xb[XB_FLOATS - 1];
            }
        }
        copy_tile(xb, out, tile);
        return;
    }
    int c = b - (b >> 2) - 1;                        // compute index among non-copy slots
    if (c < NGT)            gram_tile(p, G, c);
    else if (c < NCOMP)     cos_unit(xq, K, cosm, c - NGT);
    // else: pad block, no-op
}

// Kernel B: blocks [0,BATCH) = per-b vq (co-resident immediately, hides under
// copy), blocks [BATCH,...) = remaining copy tiles.
__global__ void kB(const double* __restrict__ cosm, const double* __restrict__ G,
                   const float* __restrict__ p, const float* __restrict__ xb,
                   float* __restrict__ out, double* __restrict__ lossAcc,
                   unsigned int* __restrict__ lossCnt) {
    if (blockIdx.x >= BATCH) {
        copy_tile(xb, out, NCOPY_A + (int)(blockIdx.x - BATCH));
        return;
    }
    int b = blockIdx.x;
    __shared__ double sa[POOL], sm[POOL];
    __shared__ double sred[4];
    __shared__ int sidx;
    int lane = threadIdx.x & 63, w = threadIdx.x >> 6;

    double cv = (threadIdx.x < POOL) ? cosm[(size_t)b * POOL + threadIdx.x] : -1.0e300;
    double m = cv;                                   // block max
    for (int off = 32; off > 0; off >>= 1) m = fmax(m, __shfl_down(m, off, 64));
    if (lane == 0) sred[w] = m;
    __syncthreads();
    m = fmax(fmax(sred[0], sred[1]), fmax(sred[2], sred[3]));
    __syncthreads();
    double e = (threadIdx.x < POOL) ? exp(cv - m) : 0.0;
    double ssum = e;                                 // block sum
    for (int off = 32; off > 0; off >>= 1) ssum += __shfl_down(ssum, off, 64);
    if (lane == 0) sred[w] = ssum;
    __syncthreads();
    ssum = sred[0] + sred[1] + sred[2] + sred[3];
    __syncthreads();
    if (threadIdx.x < POOL) sa[threadIdx.x] = e / ssum;   // alpha
    __syncthreads();
    double c = 0.0, paterm = 0.0;
    if (threadIdx.x < POOL) {
        #pragma unroll 4
        for (int k = 0; k < POOL; ++k)
            c += sa[k] * G[k * POOL + threadIdx.x];       // coalesced over tid
        paterm = sa[threadIdx.x] * c;
        sm[threadIdx.x] = G[threadIdx.x * POOL + threadIdx.x] - 2.0 * c;
    }
    double pa = paterm;                               // pa_sq block sum
    for (int off = 32; off > 0; off >>= 1) pa += __shfl_down(pa, off, 64);
    if (lane == 0) sred[w] = pa;
    __syncthreads();                                  // also fences sm[]
    pa = sred[0] + sred[1] + sred[2] + sred[3];
    if (threadIdx.x == 0) {
        int best = 0; double bm = sm[0];
        for (int k = 1; k < POOL; ++k)
            if (sm[k] < bm) { bm = sm[k]; best = k; }     // first-index tiebreak = np.argmin
        sidx = best;
        double dterm = pa + bm;    // = pa_sq - 2*cross[idx] + pp_sq[idx]
        atomicAdd(lossAcc, dterm);
        __threadfence();
        unsigned int old = atomicAdd(lossCnt, 1u);
        if (old == BATCH - 1) {
            double total = atomicAdd(lossAcc, 0.0);       // fresh read
            double msq = total / (double)(BATCH * PLEN * EMB);
            out[LOSS_OFF] = (float)(0.5 * msq);           // 0.4*e + 0.1*q, e==q numerically
        }
    }
    __syncthreads();
    int idx = sidx;
    const float4* src = (const float4*)(p + (size_t)idx * LD);
    float4* ek = (float4*)out;
    float4* ev = (float4*)(out + EK_FLOATS);
    for (int j = threadIdx.x; j < LD / 4; j += 256) {     // 1536 float4
        float4 v = src[j];
        int l = j / (EMB / 4);        // prompt-slot 0..7
        int r = j % (EMB / 4);
        if (l < 4) ek[b * EMB + l * (EMB / 4) + r] = v;
        else       ev[b * EMB + (l - 4) * (EMB / 4) + r] = v;
    }
}

extern "C" void kernel_launch(void* const* d_in, const int* in_sizes, int n_in,
                              void* d_out, int out_size, void* d_ws, size_t ws_size,
                              hipStream_t stream) {
    const float* xq = (const float*)d_in[0];
    // d_in[1] = l (always 0, in E_LAYERS)
    const float* xb = (const float*)d_in[2];
    const float* K  = (const float*)d_in[3];
    const float* p  = (const float*)d_in[4];
    float* out = (float*)d_out;

    double* G        = (double*)d_ws;          // 100*100 doubles = 80 KB
    double* cosm     = G + POOL * POOL;        // 256*100 doubles = 200 KB
    double* lossAcc  = cosm + BATCH * POOL;    // 1 double
    unsigned int* lossCnt = (unsigned int*)(lossAcc + 1);

    kA<<<GRID_A, 256, 0, stream>>>(p, xq, K, xb, out, G, cosm, lossAcc, lossCnt);
    kB<<<GRID_B, 256, 0, stream>>>(cosm, G, p, xb, out, lossAcc, lossCnt);
}

// Round 6
// 90.188 us; speedup vs baseline: 1.6620x; 1.6620x over previous
//
#include <hip/hip_runtime.h>

#define POOL 100
#define PLEN 8
#define EMB 768
#define KEYD 768
#define BATCH 256
#define LD (PLEN*EMB)              // 6144
#define EK_FLOATS (BATCH*4*EMB)    // 786432
#define XB_FLOATS (BATCH*197*EMB)  // 38756352
#define LOSS_OFF (2*EK_FLOATS)     // 1572864
#define XB_OFF (LOSS_OFF+1)        // 1572865 (4B-aligned only!)
#define NGT 325                    // 25*26/2 triangular 4x4 gram tiles
#define NCOS (BATCH*25)            // 6400 cos units, 4 waves x 25 k's each
#define NCOMP (NGT+NCOS)           // 6725 compute units
#define N4 9689087                 // (XB_FLOATS-3)/4 aligned float4 in copy
#define TILE 2048                  // float4 per copy block (256 thr x 8 iters)
#define NTILES 4731                // ceil(N4/TILE)
#define NSG 281                    // super-groups in kA: ceil(NCOMP/24)
#define GRID_A (NSG*32)            // 8992: per 32 blocks = 8 copy + 24 compute
#define NCOPY_A (NSG*8)            // 2248 copy tiles in kA
#define NCOPY_B (NTILES-NCOPY_A)   // 2483 copy tiles in kB
#define GRID_B (BATCH+NCOPY_B)     // 2739

typedef float v4f __attribute__((ext_vector_type(4)));

// Both-sides-16B-aligned streaming copy tile. dst4[j] = {src4[j].w, src4[j+1].xyz};
// src4[j].w comes from the wave neighbor via shfl_up (wave-lane 0: scalar load).
// Plain loads (m13 datum: 6.29 TB/s with plain), nontemporal stores (write-no-allocate).
__device__ __forceinline__ void copy_tile(const float* __restrict__ xb,
                                          float* __restrict__ out, int tile) {
    const v4f* src4 = (const v4f*)xb;                // 16B aligned
    v4f* dst4 = (v4f*)(out + XB_OFF + 3);            // 16B aligned
    size_t base = (size_t)tile * TILE + threadIdx.x;
    #pragma unroll
    for (int it = 0; it < 8; ++it) {
        size_t j = base + (size_t)it * 256;
        if (j < N4) {
            v4f v = src4[j + 1];
            float pw = __shfl_up(v[3], 1, 64);       // neighbor's src4[j].w
            if ((threadIdx.x & 63) == 0) pw = xb[4 * j + 3];
            v4f o = {pw, v[0], v[1], v[2]};
            __builtin_nontemporal_store(o, &dst4[j]);
        }
    }
}

// 4x4 row-group gram tile: block computes G[4gy+i][4gx+j] for i,j in 0..3.
// 8 row-loads for 16 dots, f64 accumulation.
__device__ __forceinline__ void gram_tile(const float* __restrict__ p,
                                          double* __restrict__ G, int t) {
    int gx = (int)((sqrt(8.0 * t + 1.0) - 1.0) * 0.5);
    while ((gx + 1) * (gx + 2) / 2 <= t) ++gx;
    while (gx * (gx + 1) / 2 > t) --gx;
    int gy = t - gx * (gx + 1) / 2;
    const v4f* P4 = (const v4f*)p;
    double acc[16];
    #pragma unroll
    for (int i = 0; i < 16; ++i) acc[i] = 0.0;
    #pragma unroll
    for (int ch = 0; ch < 6; ++ch) {                 // 1536 float4 cols / 256 thr
        int col = ch * 256 + threadIdx.x;
        v4f ay[4], ax[4];
        #pragma unroll
        for (int i = 0; i < 4; ++i) ay[i] = P4[(size_t)(4*gy + i) * 1536 + col];
        #pragma unroll
        for (int j = 0; j < 4; ++j) ax[j] = P4[(size_t)(4*gx + j) * 1536 + col];
        #pragma unroll
        for (int i = 0; i < 4; ++i)
            #pragma unroll
            for (int j = 0; j < 4; ++j)
                acc[i*4+j] += (double)ay[i][0]*ax[j][0] + (double)ay[i][1]*ax[j][1]
                            + (double)ay[i][2]*ax[j][2] + (double)ay[i][3]*ax[j][3];
    }
    #pragma unroll
    for (int i = 0; i < 16; ++i)
        for (int off = 32; off > 0; off >>= 1)
            acc[i] += __shfl_down(acc[i], off, 64);
    __shared__ double sg[4][16];
    int lane = threadIdx.x & 63, w = threadIdx.x >> 6;
    if (lane == 0) {
        #pragma unroll
        for (int i = 0; i < 16; ++i) sg[w][i] = acc[i];
    }
    __syncthreads();
    if (threadIdx.x < 16) {
        double v = sg[0][threadIdx.x] + sg[1][threadIdx.x]
                 + sg[2][threadIdx.x] + sg[3][threadIdx.x];
        int i = threadIdx.x >> 2, j = threadIdx.x & 3;
        int r = 4*gy + i, c = 4*gx + j;
        G[r * POOL + c] = v;     // diagonal tiles write twice w/ equal values: benign
        G[c * POOL + r] = v;
    }
}

// cos[b,k] = <xq[b],K[k]> / max(||K[k]||,1e-12), one wave per (b,k).
__device__ __forceinline__ void cos_unit(const float* __restrict__ xq,
                                         const float* __restrict__ K,
                                         double* __restrict__ cosm, int c) {
    int b = c / 25, kg = c % 25;
    int w = threadIdx.x >> 6, lane = threadIdx.x & 63;
    int k = kg * 4 + w;                              // < 100 always
    const v4f* kr = (const v4f*)(K + (size_t)k * KEYD);
    const v4f* xr = (const v4f*)(xq + (size_t)b * KEYD);
    double dot = 0.0, sq = 0.0;
    #pragma unroll
    for (int it = 0; it < 3; ++it) {                 // 192 float4 per row
        v4f a = kr[it * 64 + lane];
        v4f x = xr[it * 64 + lane];
        dot += (double)a[0]*x[0] + (double)a[1]*x[1] + (double)a[2]*x[2] + (double)a[3]*x[3];
        sq  += (double)a[0]*a[0] + (double)a[1]*a[1] + (double)a[2]*a[2] + (double)a[3]*a[3];
    }
    for (int off = 32; off > 0; off >>= 1) {
        dot += __shfl_down(dot, off, 64);
        sq  += __shfl_down(sq,  off, 64);
    }
    if (lane == 0)
        cosm[(size_t)b * POOL + k] = dot / fmax(sqrt(sq), 1e-12);
}

// Kernel A: XCD-SAFE interleave. Super-group of 32 consecutive blocks =
// 8 copy blocks (one full XCD round-robin cycle) + 24 compute blocks, so every
// XCD carries the same copy:compute mix (fix for R5's b%4 aliasing onto XCD 0/4).
__global__ void kA(const float* __restrict__ p, const float* __restrict__ xq,
                   const float* __restrict__ K, const float* __restrict__ xb,
                   float* __restrict__ out, double* __restrict__ G,
                   double* __restrict__ cosm, double* __restrict__ lossAcc,
                   unsigned int* __restrict__ lossCnt) {
    int b = blockIdx.x;
    int g = b >> 3, r = b & 7;                       // group of 8, rank in group
    int g4 = g & 3, gq = g >> 2;                     // position in super-group
    if (g4 == 0) {                                   // copy group
        int tile = gq * 8 + r;                       // 0..NCOPY_A-1
        if (tile == 0) {
            if (threadIdx.x == 64) { lossAcc[0] = 0.0; lossCnt[0] = 0u; }
            if (threadIdx.x == 65) {
                out[XB_OFF]     = xb[0];
                out[XB_OFF + 1] = xb[1];
                out[XB_OFF + 2] = xb[2];
                out[XB_OFF + XB_FLOATS - 1] = xb[XB_FLOATS - 1];
            }
        }
        copy_tile(xb, out, tile);
        return;
    }
    int c = gq * 24 + (g4 - 1) * 8 + r;              // compute unit 0..6743
    if (c < NGT)            gram_tile(p, G, c);      // heavy tiles start earliest
    else if (c < NCOMP)     cos_unit(xq, K, cosm, c - NGT);
    // else: 19 pad blocks, no-op
}

// Kernel B: blocks [0,BATCH) = per-b vq (dispatched first, co-resident, hides
// under copy), blocks [BATCH,...) = remaining copy tiles (contiguous -> all XCDs).
__global__ void kB(const double* __restrict__ cosm, const double* __restrict__ G,
                   const float* __restrict__ p, const float* __restrict__ xb,
                   float* __restrict__ out, double* __restrict__ lossAcc,
                   unsigned int* __restrict__ lossCnt) {
    if (blockIdx.x >= BATCH) {
        copy_tile(xb, out, NCOPY_A + (int)(blockIdx.x - BATCH));
        return;
    }
    int b = blockIdx.x;
    __shared__ double sa[POOL], sm[POOL];
    __shared__ double sred[4];
    __shared__ int sidx;
    int lane = threadIdx.x & 63, w = threadIdx.x >> 6;

    double cv = (threadIdx.x < POOL) ? cosm[(size_t)b * POOL + threadIdx.x] : -1.0e300;
    double m = cv;                                   // block max
    for (int off = 32; off > 0; off >>= 1) m = fmax(m, __shfl_down(m, off, 64));
    if (lane == 0) sred[w] = m;
    __syncthreads();
    m = fmax(fmax(sred[0], sred[1]), fmax(sred[2], sred[3]));
    __syncthreads();
    double e = (threadIdx.x < POOL) ? exp(cv - m) : 0.0;
    double ssum = e;                                 // block sum
    for (int off = 32; off > 0; off >>= 1) ssum += __shfl_down(ssum, off, 64);
    if (lane == 0) sred[w] = ssum;
    __syncthreads();
    ssum = sred[0] + sred[1] + sred[2] + sred[3];
    __syncthreads();
    if (threadIdx.x < POOL) sa[threadIdx.x] = e / ssum;   // alpha
    __syncthreads();
    double c = 0.0, paterm = 0.0;
    if (threadIdx.x < POOL) {
        #pragma unroll 4
        for (int k = 0; k < POOL; ++k)
            c += sa[k] * G[k * POOL + threadIdx.x];       // coalesced over tid
        paterm = sa[threadIdx.x] * c;
        sm[threadIdx.x] = G[threadIdx.x * POOL + threadIdx.x] - 2.0 * c;
    }
    double pa = paterm;                               // pa_sq block sum
    for (int off = 32; off > 0; off >>= 1) pa += __shfl_down(pa, off, 64);
    if (lane == 0) sred[w] = pa;
    __syncthreads();                                  // also fences sm[]
    pa = sred[0] + sred[1] + sred[2] + sred[3];
    if (threadIdx.x == 0) {
        int best = 0; double bm = sm[0];
        for (int k = 1; k < POOL; ++k)
            if (sm[k] < bm) { bm = sm[k]; best = k; }     // first-index tiebreak = np.argmin
        sidx = best;
        double dterm = pa + bm;    // = pa_sq - 2*cross[idx] + pp_sq[idx]
        atomicAdd(lossAcc, dterm);
        __threadfence();
        unsigned int old = atomicAdd(lossCnt, 1u);
        if (old == BATCH - 1) {
            double total = atomicAdd(lossAcc, 0.0);       // fresh read
            double msq = total / (double)(BATCH * PLEN * EMB);
            out[LOSS_OFF] = (float)(0.5 * msq);           // 0.4*e + 0.1*q, e==q numerically
        }
    }
    __syncthreads();
    int idx = sidx;
    const float4* src = (const float4*)(p + (size_t)idx * LD);
    float4* ek = (float4*)out;
    float4* ev = (float4*)(out + EK_FLOATS);
    for (int j = threadIdx.x; j < LD / 4; j += 256) {     // 1536 float4
        float4 v = src[j];
        int l = j / (EMB / 4);        // prompt-slot 0..7
        int r = j % (EMB / 4);
        if (l < 4) ek[b * EMB + l * (EMB / 4) + r] = v;
        else       ev[b * EMB + (l - 4) * (EMB / 4) + r] = v;
    }
}

extern "C" void kernel_launch(void* const* d_in, const int* in_sizes, int n_in,
                              void* d_out, int out_size, void* d_ws, size_t ws_size,
                              hipStream_t stream) {
    const float* xq = (const float*)d_in[0];
    // d_in[1] = l (always 0, in E_LAYERS)
    const float* xb = (const float*)d_in[2];
    const float* K  = (const float*)d_in[3];
    const float* p  = (const float*)d_in[4];
    float* out = (float*)d_out;

    double* G        = (double*)d_ws;          // 100*100 doubles = 80 KB
    double* cosm     = G + POOL * POOL;        // 256*100 doubles = 200 KB
    double* lossAcc  = cosm + BATCH * POOL;    // 1 double
    unsigned int* lossCnt = (unsigned int*)(lossAcc + 1);

    kA<<<GRID_A, 256, 0, stream>>>(p, xq, K, xb, out, G, cosm, lossAcc, lossCnt);
    kB<<<GRID_B, 256, 0, stream>>>(cosm, G, p, xb, out, lossAcc, lossCnt);
}